// Round 1
// baseline (674.763 us; speedup 1.0000x reference)
//
#include <hip/hip_runtime.h>
#include <math.h>

#define NTOK 2048
#define DMODEL 1024
#define NHEAD 16
#define DHEAD 64

// ---------------- shared GEMM body: C[2048x1024] = A[2048x1024] @ W[1024x1024] + bias ----------------
// 64x64 block tile, 256 threads (16x16), 4x4 per-thread tile, K-tile 16.
__device__ __forceinline__ void gemm_body(const float* __restrict__ A,
                                          const float* __restrict__ W,
                                          const float* __restrict__ bias,
                                          float* __restrict__ C) {
    __shared__ float As[16][68];   // [k][m], padded (68*4B stride: 16B-aligned float4 rows, 2-way banks)
    __shared__ float Bs[16][64];   // [k][n]
    const int t  = threadIdx.x;
    const int tx = t & 15;
    const int ty = t >> 4;
    const int row0 = blockIdx.y * 64;
    const int col0 = blockIdx.x * 64;

    const int ar = t >> 2;          // 0..63  (A row within tile)
    const int ac = (t & 3) * 4;     // 0,4,8,12
    const int wr = t >> 4;          // 0..15  (W row within k-tile)
    const int wc = (t & 15) * 4;

    float acc[4][4] = {{0.f}};

    for (int k0 = 0; k0 < DMODEL; k0 += 16) {
        const float4 av = *(const float4*)(A + (size_t)(row0 + ar) * DMODEL + k0 + ac);
        As[ac + 0][ar] = av.x;
        As[ac + 1][ar] = av.y;
        As[ac + 2][ar] = av.z;
        As[ac + 3][ar] = av.w;
        *(float4*)(&Bs[wr][wc]) = *(const float4*)(W + (size_t)(k0 + wr) * DMODEL + col0 + wc);
        __syncthreads();
#pragma unroll
        for (int kk = 0; kk < 16; ++kk) {
            const float4 a = *(const float4*)(&As[kk][ty * 4]);
            const float4 b = *(const float4*)(&Bs[kk][tx * 4]);
            acc[0][0] += a.x * b.x; acc[0][1] += a.x * b.y; acc[0][2] += a.x * b.z; acc[0][3] += a.x * b.w;
            acc[1][0] += a.y * b.x; acc[1][1] += a.y * b.y; acc[1][2] += a.y * b.z; acc[1][3] += a.y * b.w;
            acc[2][0] += a.z * b.x; acc[2][1] += a.z * b.y; acc[2][2] += a.z * b.z; acc[2][3] += a.z * b.w;
            acc[3][0] += a.w * b.x; acc[3][1] += a.w * b.y; acc[3][2] += a.w * b.z; acc[3][3] += a.w * b.w;
        }
        __syncthreads();
    }
    const float4 bb = *(const float4*)(bias + col0 + tx * 4);
#pragma unroll
    for (int i = 0; i < 4; ++i) {
        float4 o;
        o.x = acc[i][0] + bb.x;
        o.y = acc[i][1] + bb.y;
        o.z = acc[i][2] + bb.z;
        o.w = acc[i][3] + bb.w;
        *(float4*)(C + (size_t)(row0 + ty * 4 + i) * DMODEL + col0 + tx * 4) = o;
    }
}

__global__ void __launch_bounds__(256) qkv_proj_kernel(
        const float* __restrict__ q_in, const float* __restrict__ k_in, const float* __restrict__ v_in,
        const float* __restrict__ Wq, const float* __restrict__ bq,
        const float* __restrict__ Wk, const float* __restrict__ bk,
        const float* __restrict__ Wv, const float* __restrict__ bv,
        float* __restrict__ Q, float* __restrict__ K, float* __restrict__ V) {
    const float* A; const float* W; const float* b; float* C;
    if (blockIdx.z == 0)      { A = q_in; W = Wq; b = bq; C = Q; }
    else if (blockIdx.z == 1) { A = k_in; W = Wk; b = bk; C = K; }
    else                      { A = v_in; W = Wv; b = bv; C = V; }
    gemm_body(A, W, b, C);
}

__global__ void __launch_bounds__(256) out_proj_kernel(
        const float* __restrict__ X, const float* __restrict__ Wo,
        const float* __restrict__ bo, float* __restrict__ out) {
    gemm_body(X, Wo, bo, out);
}

// ---------------- pass A: raw scores + online row max/sum ----------------
// One workgroup = one head x 32 query rows. Thread (tx,ty): rows ty*2..+1, cols tx*4..+3 of each 64-col tile.
__global__ void __launch_bounds__(256) scores_kernel(
        const float* __restrict__ Q, const float* __restrict__ K,
        float* __restrict__ attn, float* __restrict__ rowM, float* __restrict__ rowL) {
    __shared__ float Qs[64][34];   // [d][r]
    __shared__ float Ks[64][68];   // [d][j]
    const int t  = threadIdx.x;
    const int tx = t & 15;
    const int ty = t >> 4;
    const int h  = blockIdx.y;
    const int r0 = blockIdx.x * 32;

#pragma unroll
    for (int i = 0; i < 2; ++i) {
        const int idx = t + i * 256;
        const int r   = idx >> 4;
        const int c4  = (idx & 15) * 4;
        const float4 qv = *(const float4*)(Q + (size_t)(r0 + r) * DMODEL + h * DHEAD + c4);
        Qs[c4 + 0][r] = qv.x;
        Qs[c4 + 1][r] = qv.y;
        Qs[c4 + 2][r] = qv.z;
        Qs[c4 + 3][r] = qv.w;
    }

    float m0 = -1e30f, m1 = -1e30f, l0 = 0.f, l1 = 0.f;

    for (int j0 = 0; j0 < NTOK; j0 += 64) {
        __syncthreads();
#pragma unroll
        for (int i = 0; i < 4; ++i) {
            const int idx = t + i * 256;
            const int jr  = idx >> 4;
            const int c4  = (idx & 15) * 4;
            const float4 kv = *(const float4*)(K + (size_t)(j0 + jr) * DMODEL + h * DHEAD + c4);
            Ks[c4 + 0][jr] = kv.x;
            Ks[c4 + 1][jr] = kv.y;
            Ks[c4 + 2][jr] = kv.z;
            Ks[c4 + 3][jr] = kv.w;
        }
        __syncthreads();

        float s0[4] = {0.f, 0.f, 0.f, 0.f};
        float s1[4] = {0.f, 0.f, 0.f, 0.f};
#pragma unroll
        for (int d = 0; d < DHEAD; ++d) {
            const float2 qv = *(const float2*)(&Qs[d][ty * 2]);
            const float4 kv = *(const float4*)(&Ks[d][tx * 4]);
            s0[0] += qv.x * kv.x; s0[1] += qv.x * kv.y; s0[2] += qv.x * kv.z; s0[3] += qv.x * kv.w;
            s1[0] += qv.y * kv.x; s1[1] += qv.y * kv.y; s1[2] += qv.y * kv.z; s1[3] += qv.y * kv.w;
        }
#pragma unroll
        for (int c = 0; c < 4; ++c) { s0[c] *= 0.125f; s1[c] *= 0.125f; }

        const size_t off0 = ((size_t)h * NTOK + r0 + ty * 2 + 0) * NTOK + j0 + tx * 4;
        *(float4*)(attn + off0)        = make_float4(s0[0], s0[1], s0[2], s0[3]);
        *(float4*)(attn + off0 + NTOK) = make_float4(s1[0], s1[1], s1[2], s1[3]);

        float tm0 = fmaxf(fmaxf(s0[0], s0[1]), fmaxf(s0[2], s0[3]));
        float tm1 = fmaxf(fmaxf(s1[0], s1[1]), fmaxf(s1[2], s1[3]));
#pragma unroll
        for (int o = 1; o < 16; o <<= 1) {
            tm0 = fmaxf(tm0, __shfl_xor(tm0, o, 16));
            tm1 = fmaxf(tm1, __shfl_xor(tm1, o, 16));
        }
        const float n0 = fmaxf(m0, tm0);
        const float n1 = fmaxf(m1, tm1);
        float ts0 = __expf(s0[0] - n0) + __expf(s0[1] - n0) + __expf(s0[2] - n0) + __expf(s0[3] - n0);
        float ts1 = __expf(s1[0] - n1) + __expf(s1[1] - n1) + __expf(s1[2] - n1) + __expf(s1[3] - n1);
#pragma unroll
        for (int o = 1; o < 16; o <<= 1) {
            ts0 += __shfl_xor(ts0, o, 16);
            ts1 += __shfl_xor(ts1, o, 16);
        }
        l0 = l0 * __expf(m0 - n0) + ts0;
        l1 = l1 * __expf(m1 - n1) + ts1;
        m0 = n0; m1 = n1;
    }

    if (tx == 0) {
        rowM[h * NTOK + r0 + ty * 2 + 0] = m0;
        rowM[h * NTOK + r0 + ty * 2 + 1] = m1;
        rowL[h * NTOK + r0 + ty * 2 + 0] = l0;
        rowL[h * NTOK + r0 + ty * 2 + 1] = l1;
    }
}

// ---------------- pass B: normalize attn in-place + X = P @ V ----------------
__global__ void __launch_bounds__(256) attnv_kernel(
        const float* __restrict__ V, const float* __restrict__ rowM, const float* __restrict__ rowL,
        float* __restrict__ attn, float* __restrict__ X) {
    __shared__ float Ps[64][34];   // [j][r]
    __shared__ float Vs[64][68];   // [j][d]
    const int t  = threadIdx.x;
    const int tx = t & 15;
    const int ty = t >> 4;
    const int h  = blockIdx.y;
    const int r0 = blockIdx.x * 32;

    const float mv0 = rowM[h * NTOK + r0 + ty * 2 + 0];
    const float mv1 = rowM[h * NTOK + r0 + ty * 2 + 1];
    const float il0 = 1.0f / rowL[h * NTOK + r0 + ty * 2 + 0];
    const float il1 = 1.0f / rowL[h * NTOK + r0 + ty * 2 + 1];

    float x0[4] = {0.f, 0.f, 0.f, 0.f};
    float x1[4] = {0.f, 0.f, 0.f, 0.f};

    for (int j0 = 0; j0 < NTOK; j0 += 64) {
        __syncthreads();
#pragma unroll
        for (int i = 0; i < 4; ++i) {
            const int idx = t + i * 256;
            const int jr  = idx >> 4;
            const int c4  = (idx & 15) * 4;
            *(float4*)(&Vs[jr][c4]) = *(const float4*)(V + (size_t)(j0 + jr) * DMODEL + h * DHEAD + c4);
        }
        const size_t off0 = ((size_t)h * NTOK + r0 + ty * 2 + 0) * NTOK + j0 + tx * 4;
        const float4 sv0 = *(const float4*)(attn + off0);
        const float4 sv1 = *(const float4*)(attn + off0 + NTOK);
        float4 p0, p1;
        p0.x = __expf(sv0.x - mv0) * il0;
        p0.y = __expf(sv0.y - mv0) * il0;
        p0.z = __expf(sv0.z - mv0) * il0;
        p0.w = __expf(sv0.w - mv0) * il0;
        p1.x = __expf(sv1.x - mv1) * il1;
        p1.y = __expf(sv1.y - mv1) * il1;
        p1.z = __expf(sv1.z - mv1) * il1;
        p1.w = __expf(sv1.w - mv1) * il1;
        *(float4*)(attn + off0)        = p0;
        *(float4*)(attn + off0 + NTOK) = p1;
        Ps[tx * 4 + 0][ty * 2 + 0] = p0.x;
        Ps[tx * 4 + 1][ty * 2 + 0] = p0.y;
        Ps[tx * 4 + 2][ty * 2 + 0] = p0.z;
        Ps[tx * 4 + 3][ty * 2 + 0] = p0.w;
        Ps[tx * 4 + 0][ty * 2 + 1] = p1.x;
        Ps[tx * 4 + 1][ty * 2 + 1] = p1.y;
        Ps[tx * 4 + 2][ty * 2 + 1] = p1.z;
        Ps[tx * 4 + 3][ty * 2 + 1] = p1.w;
        __syncthreads();
#pragma unroll
        for (int j = 0; j < 64; ++j) {
            const float2 pv = *(const float2*)(&Ps[j][ty * 2]);
            const float4 vv = *(const float4*)(&Vs[j][tx * 4]);
            x0[0] += pv.x * vv.x; x0[1] += pv.x * vv.y; x0[2] += pv.x * vv.z; x0[3] += pv.x * vv.w;
            x1[0] += pv.y * vv.x; x1[1] += pv.y * vv.y; x1[2] += pv.y * vv.z; x1[3] += pv.y * vv.w;
        }
    }
    *(float4*)(X + (size_t)(r0 + ty * 2 + 0) * DMODEL + h * DHEAD + tx * 4) = make_float4(x0[0], x0[1], x0[2], x0[3]);
    *(float4*)(X + (size_t)(r0 + ty * 2 + 1) * DMODEL + h * DHEAD + tx * 4) = make_float4(x1[0], x1[1], x1[2], x1[3]);
}

extern "C" void kernel_launch(void* const* d_in, const int* in_sizes, int n_in,
                              void* d_out, int out_size, void* d_ws, size_t ws_size,
                              hipStream_t stream) {
    (void)in_sizes; (void)n_in; (void)out_size; (void)ws_size;
    const float* query = (const float*)d_in[0];
    const float* key_  = (const float*)d_in[1];
    const float* value = (const float*)d_in[2];
    const float* Wq = (const float*)d_in[3];
    const float* bq = (const float*)d_in[4];
    const float* Wk = (const float*)d_in[5];
    const float* bk = (const float*)d_in[6];
    const float* Wv = (const float*)d_in[7];
    const float* bv = (const float*)d_in[8];
    const float* Wo = (const float*)d_in[9];
    const float* bo = (const float*)d_in[10];

    float* out  = (float*)d_out;
    float* attn = out + (size_t)NTOK * DMODEL;   // attn tensor lives directly in d_out

    float* Q    = (float*)d_ws;                  // ws usage: 4*8MB + 256KB = ~33.8MB
    float* K    = Q + (size_t)NTOK * DMODEL;
    float* V    = K + (size_t)NTOK * DMODEL;
    float* X    = V + (size_t)NTOK * DMODEL;
    float* rowM = X + (size_t)NTOK * DMODEL;
    float* rowL = rowM + (size_t)NHEAD * NTOK;

    dim3 blk(256);
    dim3 gproj(DMODEL / 64, NTOK / 64, 3);
    qkv_proj_kernel<<<gproj, blk, 0, stream>>>(query, key_, value, Wq, bq, Wk, bk, Wv, bv, Q, K, V);

    dim3 gattn(NTOK / 32, NHEAD);
    scores_kernel<<<gattn, blk, 0, stream>>>(Q, K, attn, rowM, rowL);
    attnv_kernel<<<gattn, blk, 0, stream>>>(V, rowM, rowL, attn, X);

    dim3 gout(DMODEL / 64, NTOK / 64);
    out_proj_kernel<<<gout, blk, 0, stream>>>(X, Wo, bo, out);
}

// Round 2
// 267.724 us; speedup vs baseline: 2.5204x; 2.5204x over previous
//
#include <hip/hip_runtime.h>
#include <math.h>

#define NTOK 2048
#define DMODEL 1024
#define NHEAD 16
#define DHEAD 64

typedef _Float16 f16x8 __attribute__((ext_vector_type(8)));
typedef _Float16 f16x4 __attribute__((ext_vector_type(4)));
typedef float f32x4 __attribute__((ext_vector_type(4)));

__device__ __forceinline__ void split16(float x, _Float16& hi, _Float16& lo) {
    hi = (_Float16)x;
    lo = (_Float16)(x - (float)hi);
}

// ---------- prep: W[k][n] f32 -> Wt_hi/Wt_lo [n][k] f16, 4 matrices ----------
__global__ void __launch_bounds__(256) prep_w_kernel(
        const float* __restrict__ Wq, const float* __restrict__ Wk,
        const float* __restrict__ Wv, const float* __restrict__ Wo,
        _Float16* __restrict__ Wt) {
    __shared__ float T[32][33];
    const int z = blockIdx.z;
    const float* W = (z == 0) ? Wq : (z == 1) ? Wk : (z == 2) ? Wv : Wo;
    _Float16* Whi = Wt + (size_t)z * 2 * 1024 * 1024;
    _Float16* Wlo = Whi + (size_t)1024 * 1024;
    const int t = threadIdx.x;
    const int k0 = blockIdx.y * 32, n0 = blockIdx.x * 32;
    const int r = t >> 3, c4 = (t & 7) * 4;
    const float4 v = *(const float4*)(W + (size_t)(k0 + r) * DMODEL + n0 + c4);
    T[r][c4 + 0] = v.x; T[r][c4 + 1] = v.y; T[r][c4 + 2] = v.z; T[r][c4 + 3] = v.w;
    __syncthreads();
    f16x4 hv, lv;
#pragma unroll
    for (int j = 0; j < 4; ++j) {
        _Float16 h, l;
        split16(T[c4 + j][r], h, l);
        hv[j] = h; lv[j] = l;
    }
    *(f16x4*)(Whi + (size_t)(n0 + r) * DMODEL + k0 + c4) = hv;
    *(f16x4*)(Wlo + (size_t)(n0 + r) * DMODEL + k0 + c4) = lv;
}

// ---------- QKV projection: split-f16 MFMA GEMM ----------
// C[2048x1024] = A(f32) @ W + b. 128x128 tile, 4 waves (2x2), wave=64x64, BK=32.
__global__ void __launch_bounds__(256) qkv_mfma_kernel(
        const float* __restrict__ Aq, const float* __restrict__ Ak, const float* __restrict__ Av,
        const _Float16* __restrict__ Wt,
        const float* __restrict__ bq, const float* __restrict__ bk, const float* __restrict__ bv,
        _Float16* __restrict__ Qh, _Float16* __restrict__ Ql,
        _Float16* __restrict__ Kh, _Float16* __restrict__ Kl,
        _Float16* __restrict__ Vth, _Float16* __restrict__ Vtl) {
    __shared__ _Float16 Ah[128][40], Al[128][40], Bh[128][40], Bl[128][40];
    const int z = blockIdx.z;
    const float* A = (z == 0) ? Aq : (z == 1) ? Ak : Av;
    const _Float16* WH = Wt + (size_t)z * 2 * 1024 * 1024;
    const _Float16* WL = WH + (size_t)1024 * 1024;
    const float* bias = (z == 0) ? bq : (z == 1) ? bk : bv;

    const int t = threadIdx.x;
    const int l = t & 63, wid = t >> 6;
    const int lr = l & 15, lk = l >> 4;
    const int m0 = blockIdx.y * 128, n0 = blockIdx.x * 128;
    const int wm = (wid >> 1) * 64, wn = (wid & 1) * 64;

    f32x4 acc[4][4];
#pragma unroll
    for (int mi = 0; mi < 4; ++mi)
#pragma unroll
        for (int ni = 0; ni < 4; ++ni)
#pragma unroll
            for (int e = 0; e < 4; ++e) acc[mi][ni][e] = 0.f;

    for (int k0 = 0; k0 < DMODEL; k0 += 32) {
        __syncthreads();
#pragma unroll
        for (int p = 0; p < 4; ++p) {                    // A: f32 -> hi/lo f16
            const int idx = t + p * 256;
            const int r = idx >> 3, c4 = (idx & 7) * 4;
            const float4 v = *(const float4*)(A + (size_t)(m0 + r) * DMODEL + k0 + c4);
            f16x4 hv, lv; _Float16 h, lo;
            split16(v.x, h, lo); hv[0] = h; lv[0] = lo;
            split16(v.y, h, lo); hv[1] = h; lv[1] = lo;
            split16(v.z, h, lo); hv[2] = h; lv[2] = lo;
            split16(v.w, h, lo); hv[3] = h; lv[3] = lo;
            *(f16x4*)&Ah[r][c4] = hv;
            *(f16x4*)&Al[r][c4] = lv;
        }
#pragma unroll
        for (int p = 0; p < 2; ++p) {                    // B: prepped f16 direct
            const int idx = t + p * 256;
            const int r = idx >> 2, c8 = (idx & 3) * 8;
            *(f16x8*)&Bh[r][c8] = *(const f16x8*)(WH + (size_t)(n0 + r) * DMODEL + k0 + c8);
            *(f16x8*)&Bl[r][c8] = *(const f16x8*)(WL + (size_t)(n0 + r) * DMODEL + k0 + c8);
        }
        __syncthreads();

        f16x8 ah[4], al[4], bh[4], bl[4];
#pragma unroll
        for (int i = 0; i < 4; ++i) {
            ah[i] = *(f16x8*)&Ah[wm + i * 16 + lr][lk * 8];
            al[i] = *(f16x8*)&Al[wm + i * 16 + lr][lk * 8];
            bh[i] = *(f16x8*)&Bh[wn + i * 16 + lr][lk * 8];
            bl[i] = *(f16x8*)&Bl[wn + i * 16 + lr][lk * 8];
        }
#pragma unroll
        for (int mi = 0; mi < 4; ++mi)
#pragma unroll
            for (int ni = 0; ni < 4; ++ni) {
                acc[mi][ni] = __builtin_amdgcn_mfma_f32_16x16x32_f16(ah[mi], bh[ni], acc[mi][ni], 0, 0, 0);
                acc[mi][ni] = __builtin_amdgcn_mfma_f32_16x16x32_f16(ah[mi], bl[ni], acc[mi][ni], 0, 0, 0);
                acc[mi][ni] = __builtin_amdgcn_mfma_f32_16x16x32_f16(al[mi], bh[ni], acc[mi][ni], 0, 0, 0);
            }
    }

    // epilogue: z=0 -> Q*(1/8) hi/lo; z=1 -> K hi/lo; z=2 -> V transposed hi/lo
#pragma unroll
    for (int ni = 0; ni < 4; ++ni) {
        const int col = n0 + wn + ni * 16 + lr;
        const float bv_ = bias[col];
#pragma unroll
        for (int mi = 0; mi < 4; ++mi) {
            if (z == 2) {
                f16x4 hv, lv;
#pragma unroll
                for (int i = 0; i < 4; ++i) {
                    _Float16 h, lo;
                    split16(acc[mi][ni][i] + bv_, h, lo);
                    hv[i] = h; lv[i] = lo;
                }
                const int row = m0 + wm + mi * 16 + lk * 4;
                *(f16x4*)(Vth + (size_t)col * NTOK + row) = hv;
                *(f16x4*)(Vtl + (size_t)col * NTOK + row) = lv;
            } else {
#pragma unroll
                for (int i = 0; i < 4; ++i) {
                    const int row = m0 + wm + mi * 16 + lk * 4 + i;
                    float v = acc[mi][ni][i] + bv_;
                    if (z == 0) v *= 0.125f;
                    _Float16 h, lo;
                    split16(v, h, lo);
                    if (z == 0) { Qh[(size_t)row * DMODEL + col] = h; Ql[(size_t)row * DMODEL + col] = lo; }
                    else        { Kh[(size_t)row * DMODEL + col] = h; Kl[(size_t)row * DMODEL + col] = lo; }
                }
            }
        }
    }
}

// ---------- fused attention: 2-pass (stats, then attn-write + PV), all MFMA ----------
// Block: 1 head x 64 q-rows; 4 waves x 16 rows each.
__global__ void __launch_bounds__(256) attn_kernel(
        const _Float16* __restrict__ Qh, const _Float16* __restrict__ Ql,
        const _Float16* __restrict__ Kh, const _Float16* __restrict__ Kl,
        const _Float16* __restrict__ Vth, const _Float16* __restrict__ Vtl,
        float* __restrict__ attn, _Float16* __restrict__ Xh, _Float16* __restrict__ Xl) {
    __shared__ _Float16 Ksh[64][72], Ksl[64][72], Vsh[64][72], Vsl[64][72];
    __shared__ _Float16 Ph[4][16][72], Pl[4][16][72];
    const int t = threadIdx.x;
    const int l = t & 63, wid = t >> 6;
    const int lr = l & 15, lk = l >> 4;
    const int h = blockIdx.y;
    const int rw = blockIdx.x * 64 + wid * 16;

    f16x8 qh[2], qlo[2];
#pragma unroll
    for (int s = 0; s < 2; ++s) {
        qh[s]  = *(const f16x8*)(Qh + (size_t)(rw + lr) * DMODEL + h * DHEAD + s * 32 + lk * 8);
        qlo[s] = *(const f16x8*)(Ql + (size_t)(rw + lr) * DMODEL + h * DHEAD + s * 32 + lk * 8);
    }

    float m[4], lsum[4];
#pragma unroll
    for (int i = 0; i < 4; ++i) { m[i] = -1e30f; lsum[i] = 0.f; }

    // ---- pass 1: stats only ----
    for (int j0 = 0; j0 < NTOK; j0 += 64) {
        __syncthreads();
#pragma unroll
        for (int p = 0; p < 2; ++p) {
            const int idx = t + p * 256;
            const int jr = idx >> 3, c8 = (idx & 7) * 8;
            *(f16x8*)&Ksh[jr][c8] = *(const f16x8*)(Kh + (size_t)(j0 + jr) * DMODEL + h * DHEAD + c8);
            *(f16x8*)&Ksl[jr][c8] = *(const f16x8*)(Kl + (size_t)(j0 + jr) * DMODEL + h * DHEAD + c8);
        }
        __syncthreads();

        f32x4 s[4];
#pragma unroll
        for (int jt = 0; jt < 4; ++jt) {
#pragma unroll
            for (int e = 0; e < 4; ++e) s[jt][e] = 0.f;
#pragma unroll
            for (int ks = 0; ks < 2; ++ks) {
                const f16x8 kh = *(f16x8*)&Ksh[jt * 16 + lr][ks * 32 + lk * 8];
                const f16x8 kl = *(f16x8*)&Ksl[jt * 16 + lr][ks * 32 + lk * 8];
                s[jt] = __builtin_amdgcn_mfma_f32_16x16x32_f16(qh[ks], kh, s[jt], 0, 0, 0);
                s[jt] = __builtin_amdgcn_mfma_f32_16x16x32_f16(qh[ks], kl, s[jt], 0, 0, 0);
                s[jt] = __builtin_amdgcn_mfma_f32_16x16x32_f16(qlo[ks], kh, s[jt], 0, 0, 0);
            }
        }
#pragma unroll
        for (int i = 0; i < 4; ++i) {
            float v = fmaxf(fmaxf(s[0][i], s[1][i]), fmaxf(s[2][i], s[3][i]));
#pragma unroll
            for (int o = 1; o < 16; o <<= 1) v = fmaxf(v, __shfl_xor(v, o, 16));
            const float mn = fmaxf(m[i], v);
            float e = __expf(s[0][i] - mn) + __expf(s[1][i] - mn) +
                      __expf(s[2][i] - mn) + __expf(s[3][i] - mn);
#pragma unroll
            for (int o = 1; o < 16; o <<= 1) e += __shfl_xor(e, o, 16);
            lsum[i] = lsum[i] * __expf(m[i] - mn) + e;
            m[i] = mn;
        }
    }

    float linv[4];
#pragma unroll
    for (int i = 0; i < 4; ++i) linv[i] = 1.0f / lsum[i];

    f32x4 x[4];
#pragma unroll
    for (int dt = 0; dt < 4; ++dt)
#pragma unroll
        for (int e = 0; e < 4; ++e) x[dt][e] = 0.f;

    // ---- pass 2: recompute scores, write attn, PV ----
    for (int j0 = 0; j0 < NTOK; j0 += 64) {
        __syncthreads();
#pragma unroll
        for (int p = 0; p < 2; ++p) {
            const int idx = t + p * 256;
            const int jr = idx >> 3, c8 = (idx & 7) * 8;
            *(f16x8*)&Ksh[jr][c8] = *(const f16x8*)(Kh + (size_t)(j0 + jr) * DMODEL + h * DHEAD + c8);
            *(f16x8*)&Ksl[jr][c8] = *(const f16x8*)(Kl + (size_t)(j0 + jr) * DMODEL + h * DHEAD + c8);
            *(f16x8*)&Vsh[jr][c8] = *(const f16x8*)(Vth + (size_t)(h * DHEAD + jr) * NTOK + j0 + c8);
            *(f16x8*)&Vsl[jr][c8] = *(const f16x8*)(Vtl + (size_t)(h * DHEAD + jr) * NTOK + j0 + c8);
        }
        __syncthreads();

        f32x4 s[4];
#pragma unroll
        for (int jt = 0; jt < 4; ++jt) {
#pragma unroll
            for (int e = 0; e < 4; ++e) s[jt][e] = 0.f;
#pragma unroll
            for (int ks = 0; ks < 2; ++ks) {
                const f16x8 kh = *(f16x8*)&Ksh[jt * 16 + lr][ks * 32 + lk * 8];
                const f16x8 kl = *(f16x8*)&Ksl[jt * 16 + lr][ks * 32 + lk * 8];
                s[jt] = __builtin_amdgcn_mfma_f32_16x16x32_f16(qh[ks], kh, s[jt], 0, 0, 0);
                s[jt] = __builtin_amdgcn_mfma_f32_16x16x32_f16(qh[ks], kl, s[jt], 0, 0, 0);
                s[jt] = __builtin_amdgcn_mfma_f32_16x16x32_f16(qlo[ks], kh, s[jt], 0, 0, 0);
            }
        }
#pragma unroll
        for (int jt = 0; jt < 4; ++jt)
#pragma unroll
            for (int i = 0; i < 4; ++i) {
                const float p = __expf(s[jt][i] - m[i]) * linv[i];
                attn[((size_t)h * NTOK + rw + lk * 4 + i) * NTOK + j0 + jt * 16 + lr] = p;
                _Float16 ph, pl;
                split16(p, ph, pl);
                Ph[wid][lk * 4 + i][jt * 16 + lr] = ph;
                Pl[wid][lk * 4 + i][jt * 16 + lr] = pl;
            }
        __syncthreads();

        f16x8 pah[2], pal[2];
#pragma unroll
        for (int ks = 0; ks < 2; ++ks) {
            pah[ks] = *(f16x8*)&Ph[wid][lr][ks * 32 + lk * 8];
            pal[ks] = *(f16x8*)&Pl[wid][lr][ks * 32 + lk * 8];
        }
#pragma unroll
        for (int dt = 0; dt < 4; ++dt)
#pragma unroll
            for (int ks = 0; ks < 2; ++ks) {
                const f16x8 vh = *(f16x8*)&Vsh[dt * 16 + lr][ks * 32 + lk * 8];
                const f16x8 vl = *(f16x8*)&Vsl[dt * 16 + lr][ks * 32 + lk * 8];
                x[dt] = __builtin_amdgcn_mfma_f32_16x16x32_f16(pah[ks], vh, x[dt], 0, 0, 0);
                x[dt] = __builtin_amdgcn_mfma_f32_16x16x32_f16(pah[ks], vl, x[dt], 0, 0, 0);
                x[dt] = __builtin_amdgcn_mfma_f32_16x16x32_f16(pal[ks], vh, x[dt], 0, 0, 0);
            }
    }

    // X epilogue -> hi/lo f16 for out-proj
#pragma unroll
    for (int dt = 0; dt < 4; ++dt)
#pragma unroll
        for (int i = 0; i < 4; ++i) {
            const int row = rw + lk * 4 + i;
            const int col = h * DHEAD + dt * 16 + lr;
            _Float16 hh, lo;
            split16(x[dt][i], hh, lo);
            Xh[(size_t)row * DMODEL + col] = hh;
            Xl[(size_t)row * DMODEL + col] = lo;
        }
}

// ---------- output projection: split-f16 MFMA GEMM, f32 epilogue ----------
__global__ void __launch_bounds__(256) out_mfma_kernel(
        const _Float16* __restrict__ Xh, const _Float16* __restrict__ Xl,
        const _Float16* __restrict__ WH, const _Float16* __restrict__ WL,
        const float* __restrict__ bo, float* __restrict__ out) {
    __shared__ _Float16 Ah[128][40], Al[128][40], Bh[128][40], Bl[128][40];
    const int t = threadIdx.x;
    const int l = t & 63, wid = t >> 6;
    const int lr = l & 15, lk = l >> 4;
    const int m0 = blockIdx.y * 128, n0 = blockIdx.x * 128;
    const int wm = (wid >> 1) * 64, wn = (wid & 1) * 64;

    f32x4 acc[4][4];
#pragma unroll
    for (int mi = 0; mi < 4; ++mi)
#pragma unroll
        for (int ni = 0; ni < 4; ++ni)
#pragma unroll
            for (int e = 0; e < 4; ++e) acc[mi][ni][e] = 0.f;

    for (int k0 = 0; k0 < DMODEL; k0 += 32) {
        __syncthreads();
#pragma unroll
        for (int p = 0; p < 2; ++p) {
            const int idx = t + p * 256;
            const int r = idx >> 2, c8 = (idx & 3) * 8;
            *(f16x8*)&Ah[r][c8] = *(const f16x8*)(Xh + (size_t)(m0 + r) * DMODEL + k0 + c8);
            *(f16x8*)&Al[r][c8] = *(const f16x8*)(Xl + (size_t)(m0 + r) * DMODEL + k0 + c8);
            *(f16x8*)&Bh[r][c8] = *(const f16x8*)(WH + (size_t)(n0 + r) * DMODEL + k0 + c8);
            *(f16x8*)&Bl[r][c8] = *(const f16x8*)(WL + (size_t)(n0 + r) * DMODEL + k0 + c8);
        }
        __syncthreads();

        f16x8 ah[4], al[4], bh[4], bl[4];
#pragma unroll
        for (int i = 0; i < 4; ++i) {
            ah[i] = *(f16x8*)&Ah[wm + i * 16 + lr][lk * 8];
            al[i] = *(f16x8*)&Al[wm + i * 16 + lr][lk * 8];
            bh[i] = *(f16x8*)&Bh[wn + i * 16 + lr][lk * 8];
            bl[i] = *(f16x8*)&Bl[wn + i * 16 + lr][lk * 8];
        }
#pragma unroll
        for (int mi = 0; mi < 4; ++mi)
#pragma unroll
            for (int ni = 0; ni < 4; ++ni) {
                acc[mi][ni] = __builtin_amdgcn_mfma_f32_16x16x32_f16(ah[mi], bh[ni], acc[mi][ni], 0, 0, 0);
                acc[mi][ni] = __builtin_amdgcn_mfma_f32_16x16x32_f16(ah[mi], bl[ni], acc[mi][ni], 0, 0, 0);
                acc[mi][ni] = __builtin_amdgcn_mfma_f32_16x16x32_f16(al[mi], bh[ni], acc[mi][ni], 0, 0, 0);
            }
    }

#pragma unroll
    for (int ni = 0; ni < 4; ++ni) {
        const int col = n0 + wn + ni * 16 + lr;
        const float bv_ = bo[col];
#pragma unroll
        for (int mi = 0; mi < 4; ++mi)
#pragma unroll
            for (int i = 0; i < 4; ++i) {
                const int row = m0 + wm + mi * 16 + lk * 4 + i;
                out[(size_t)row * DMODEL + col] = acc[mi][ni][i] + bv_;
            }
    }
}

extern "C" void kernel_launch(void* const* d_in, const int* in_sizes, int n_in,
                              void* d_out, int out_size, void* d_ws, size_t ws_size,
                              hipStream_t stream) {
    (void)in_sizes; (void)n_in; (void)out_size; (void)ws_size;
    const float* query = (const float*)d_in[0];
    const float* key_  = (const float*)d_in[1];
    const float* value = (const float*)d_in[2];
    const float* Wq = (const float*)d_in[3];
    const float* bq = (const float*)d_in[4];
    const float* Wk = (const float*)d_in[5];
    const float* bk = (const float*)d_in[6];
    const float* Wv = (const float*)d_in[7];
    const float* bv = (const float*)d_in[8];
    const float* Wo = (const float*)d_in[9];
    const float* bo = (const float*)d_in[10];

    float* out  = (float*)d_out;
    float* attn = out + (size_t)NTOK * DMODEL;

    const size_t MM = (size_t)1024 * 1024;
    _Float16* ws16 = (_Float16*)d_ws;          // total 24*MM halves = 48 MB
    _Float16* Wt  = ws16;                      // 8 planes (Wq,Wk,Wv,Wo x hi/lo)
    _Float16* Qh  = ws16 + 8 * MM;
    _Float16* Ql  = Qh  + 2 * MM;
    _Float16* Kh_ = Ql  + 2 * MM;
    _Float16* Kl_ = Kh_ + 2 * MM;
    _Float16* Vth = Kl_ + 2 * MM;
    _Float16* Vtl = Vth + 2 * MM;
    _Float16* Xh  = Vtl + 2 * MM;
    _Float16* Xl  = Xh  + 2 * MM;

    dim3 blk(256);
    prep_w_kernel<<<dim3(32, 32, 4), blk, 0, stream>>>(Wq, Wk, Wv, Wo, Wt);
    qkv_mfma_kernel<<<dim3(8, 16, 3), blk, 0, stream>>>(query, key_, value, Wt, bq, bk, bv,
                                                        Qh, Ql, Kh_, Kl_, Vth, Vtl);
    attn_kernel<<<dim3(32, 16), blk, 0, stream>>>(Qh, Ql, Kh_, Kl_, Vth, Vtl, attn, Xh, Xl);
    out_mfma_kernel<<<dim3(8, 16), blk, 0, stream>>>(Xh, Xl, Wt + 6 * MM, Wt + 7 * MM, bo, out);
}